// Round 1
// baseline (347.649 us; speedup 1.0000x reference)
//
#include <hip/hip_runtime.h>
#include <hip/hip_bf16.h>

typedef short s16x8 __attribute__((ext_vector_type(8)));
typedef short s16x4 __attribute__((ext_vector_type(4)));
typedef float f32x4 __attribute__((ext_vector_type(4)));

#define DI __device__ __forceinline__

constexpr int BB = 16;    // batch
constexpr int CC = 256;   // in channels
constexpr int MM = 4096;  // H*W
constexpr int KD = 16;    // k
constexpr int UK = 64;    // u*k
constexpr float EPSV = 1e-5f;

DI short f2bf(float f) {
  union { float f; unsigned u; } v; v.f = f;
  unsigned r = v.u + 0x7FFFu + ((v.u >> 16) & 1u);
  return (short)(r >> 16);
}

// ---------------- xsum[c] = sum over b,m of x[b,c,m] ----------------
__global__ __launch_bounds__(256) void k_xsum(const float* __restrict__ x,
                                              float* __restrict__ xsum) {
  int bid = blockIdx.x;                 // 0..4095 = b*256 + c
  int b = bid >> 8, c = bid & 255;
  const float4* p = (const float4*)(x + ((size_t)(b * CC + c)) * MM);
  int t = threadIdx.x;
  float s = 0.f;
#pragma unroll
  for (int i = 0; i < 4; ++i) {
    float4 v = p[i * 256 + t];
    s += v.x + v.y + v.z + v.w;
  }
#pragma unroll
  for (int o = 32; o; o >>= 1) s += __shfl_down(s, o);
  __shared__ float red[4];
  if ((t & 63) == 0) red[t >> 6] = s;
  __syncthreads();
  if (t == 0) atomicAdd(&xsum[c], red[0] + red[1] + red[2] + red[3]);
}

// ---------------- Q/K projection (f32 VALU, W via scalar loads) ----------------
__global__ __launch_bounds__(256) void k_proj(const float* __restrict__ x,
    const float* __restrict__ Wq, const float* __restrict__ bq,
    const float* __restrict__ Wk, const float* __restrict__ bk,
    float* __restrict__ Kb, float* __restrict__ Qb) {
  int bid = blockIdx.x;                 // 16 b * 16 mc
  int b = bid >> 4, mc = bid & 15;
  int m = mc * 256 + threadIdx.x;
  const float* xb = x + (size_t)b * CC * MM + m;
  float acc[80];
#pragma unroll
  for (int o = 0; o < 80; ++o) acc[o] = 0.f;

  float cx0 = xb[0], cx1 = xb[MM], cx2 = xb[2 * MM], cx3 = xb[3 * MM];
  for (int c = 0; c < CC; c += 4) {
    float nx0 = 0.f, nx1 = 0.f, nx2 = 0.f, nx3 = 0.f;
    if (c + 4 < CC) {
      const float* nb = xb + (size_t)(c + 4) * MM;
      nx0 = nb[0]; nx1 = nb[MM]; nx2 = nb[2 * MM]; nx3 = nb[3 * MM];
    }
#pragma unroll
    for (int o = 0; o < 64; ++o) {
      const float* wr = Wk + o * CC + c;   // uniform -> s_load_dwordx4
      float a = acc[o];
      a = fmaf(cx0, wr[0], a);
      a = fmaf(cx1, wr[1], a);
      a = fmaf(cx2, wr[2], a);
      a = fmaf(cx3, wr[3], a);
      acc[o] = a;
    }
#pragma unroll
    for (int o = 0; o < 16; ++o) {
      const float* wr = Wq + o * CC + c;
      float a = acc[64 + o];
      a = fmaf(cx0, wr[0], a);
      a = fmaf(cx1, wr[1], a);
      a = fmaf(cx2, wr[2], a);
      a = fmaf(cx3, wr[3], a);
      acc[64 + o] = a;
    }
    cx0 = nx0; cx1 = nx1; cx2 = nx2; cx3 = nx3;
  }
  float* kout = Kb + ((size_t)b * UK) * MM + m;
#pragma unroll
  for (int o = 0; o < 64; ++o) kout[(size_t)o * MM] = acc[o] + bk[o];
  float* qout = Qb + ((size_t)b * KD) * MM + m;
#pragma unroll
  for (int o = 0; o < 16; ++o) qout[(size_t)o * MM] = acc[64 + o] + bq[o];
}

// ---------------- G = sum_b x[b] x[b]^T  (bf16 MFMA, atomic accumulate) ----------------
__global__ __launch_bounds__(512) void k_gxx(const float* __restrict__ x,
                                             float* __restrict__ G) {
  int b = blockIdx.x >> 3, kc = blockIdx.x & 7;   // 16 b * 8 k-chunks of 512
  int kbase = kc * 512;
  __shared__ short lt[256][40];                   // 32 bf16 + pad 8
  int t = threadIdx.x;
  int w = t >> 6, l = t & 63;
  int wr = w >> 2, wc = w & 3;                    // wave tile: rows 128*wr, cols 64*wc
  int lrow = l & 15, lk = (l >> 4) * 8;

  f32x4 zero = {0.f, 0.f, 0.f, 0.f};
  f32x4 acc[8][4];
#pragma unroll
  for (int i = 0; i < 8; ++i)
#pragma unroll
    for (int j = 0; j < 4; ++j) acc[i][j] = zero;

  for (int ks = 0; ks < 16; ++ks) {
    int k0 = kbase + ks * 32;
    __syncthreads();
    {
      int r = t >> 1, hh = (t & 1) * 16;
      const float4* src = (const float4*)(x + ((size_t)(b * CC + r)) * MM + k0 + hh);
      s16x8 w0, w1;
#pragma unroll
      for (int i = 0; i < 2; ++i) {
        float4 v = src[i];
        w0[i * 4 + 0] = f2bf(v.x); w0[i * 4 + 1] = f2bf(v.y);
        w0[i * 4 + 2] = f2bf(v.z); w0[i * 4 + 3] = f2bf(v.w);
      }
#pragma unroll
      for (int i = 0; i < 2; ++i) {
        float4 v = src[2 + i];
        w1[i * 4 + 0] = f2bf(v.x); w1[i * 4 + 1] = f2bf(v.y);
        w1[i * 4 + 2] = f2bf(v.z); w1[i * 4 + 3] = f2bf(v.w);
      }
      *(s16x8*)&lt[r][hh] = w0;
      *(s16x8*)&lt[r][hh + 8] = w1;
    }
    __syncthreads();
    s16x8 af[8], bf[4];
#pragma unroll
    for (int i = 0; i < 8; ++i) af[i] = *(const s16x8*)&lt[wr * 128 + i * 16 + lrow][lk];
#pragma unroll
    for (int j = 0; j < 4; ++j) bf[j] = *(const s16x8*)&lt[wc * 64 + j * 16 + lrow][lk];
#pragma unroll
    for (int i = 0; i < 8; ++i)
#pragma unroll
      for (int j = 0; j < 4; ++j)
        acc[i][j] = __builtin_amdgcn_mfma_f32_16x16x32_bf16(af[i], bf[j], acc[i][j], 0, 0, 0);
  }
#pragma unroll
  for (int i = 0; i < 8; ++i)
#pragma unroll
    for (int j = 0; j < 4; ++j)
#pragma unroll
      for (int r = 0; r < 4; ++r) {
        int row = wr * 128 + i * 16 + (l >> 4) * 4 + r;
        int col = wc * 64 + j * 16 + lrow;
        atomicAdd(&G[row * 256 + col], acc[i][j][r]);
      }
}

// ---------------- softmax row stats over K ----------------
__global__ __launch_bounds__(256) void k_sstats(const float* __restrict__ Kb,
    float* __restrict__ rmax, float* __restrict__ rsum) {
  int r = blockIdx.x;                    // 0..1023
  int t = threadIdx.x;
  const float4* p = (const float4*)(Kb + (size_t)r * MM);
  float4 v[4];
  float mx = -3.4e38f;
#pragma unroll
  for (int i = 0; i < 4; ++i) {
    v[i] = p[i * 256 + t];
    mx = fmaxf(mx, fmaxf(fmaxf(v[i].x, v[i].y), fmaxf(v[i].z, v[i].w)));
  }
#pragma unroll
  for (int o = 32; o; o >>= 1) mx = fmaxf(mx, __shfl_xor(mx, o));
  __shared__ float red[4];
  int w = t >> 6;
  if ((t & 63) == 0) red[w] = mx;
  __syncthreads();
  mx = fmaxf(fmaxf(red[0], red[1]), fmaxf(red[2], red[3]));
  float s = 0.f;
#pragma unroll
  for (int i = 0; i < 4; ++i)
    s += __expf(v[i].x - mx) + __expf(v[i].y - mx) +
         __expf(v[i].z - mx) + __expf(v[i].w - mx);
#pragma unroll
  for (int o = 32; o; o >>= 1) s += __shfl_xor(s, o);
  __syncthreads();
  if ((t & 63) == 0) red[w] = s;
  __syncthreads();
  if (t == 0) {
    rmax[r] = mx;
    rsum[r] = red[0] + red[1] + red[2] + red[3];
  }
}

// ---------------- BN affine params from G, xsum ----------------
__global__ __launch_bounds__(256) void k_fin(const float* __restrict__ G,
    const float* __restrict__ xsum,
    const float* __restrict__ Wv, const float* __restrict__ bv,
    const float* __restrict__ gv, const float* __restrict__ btv,
    const float* __restrict__ Wq, const float* __restrict__ bq,
    const float* __restrict__ gq, const float* __restrict__ btq,
    float* __restrict__ AV, float* __restrict__ BVa,
    float* __restrict__ AQ, float* __restrict__ BQa) {
  int o = blockIdx.x;                    // 0..1039: 0..1023 V-ch, 1024.. Q-ch
  int t = threadIdx.x;
  const float* w; float bias, gamma, beta; float* pa; float* pb;
  if (o < 1024) {
    w = Wv + (size_t)o * CC; bias = bv[o]; gamma = gv[o]; beta = btv[o];
    pa = AV + o; pb = BVa + o;
  } else {
    int oi = o - 1024;
    w = Wq + (size_t)oi * CC; bias = bq[oi]; gamma = gq[oi]; beta = btq[oi];
    pa = AQ + oi; pb = BQa + oi;
  }
  __shared__ float lw[256];
  lw[t] = w[t];
  __syncthreads();
  const float* g = G + (size_t)t * CC;
  float tv = 0.f;
#pragma unroll 8
  for (int c = 0; c < CC; c += 4) {
    float4 g4 = *(const float4*)(g + c);
    tv += g4.x * lw[c] + g4.y * lw[c + 1] + g4.z * lw[c + 2] + g4.w * lw[c + 3];
  }
  float qf = tv * lw[t];
  float sx = lw[t] * xsum[t];
#pragma unroll
  for (int od = 32; od; od >>= 1) { qf += __shfl_xor(qf, od); sx += __shfl_xor(sx, od); }
  __shared__ float r1[4], r2[4];
  int wv = t >> 6;
  if ((t & 63) == 0) { r1[wv] = qf; r2[wv] = sx; }
  __syncthreads();
  if (t == 0) {
    qf = r1[0] + r1[1] + r1[2] + r1[3];
    sx = r2[0] + r2[1] + r2[2] + r2[3];
    const float invN = 1.f / 65536.f;
    float mean = sx * invN + bias;
    float e2 = qf * invN + 2.f * bias * sx * invN + bias * bias;
    float var = e2 - mean * mean;
    float a = gamma * rsqrtf(var + EPSV);
    *pa = a;
    *pb = beta - mean * a;
  }
}

// ---------------- xp[b,j,c] = sum_m exp(K[b,j,m]-rmax) * x[b,c,m]  (bf16 MFMA) ----------------
__global__ __launch_bounds__(256) void k_xp(const float* __restrict__ x,
    const float* __restrict__ Kb, const float* __restrict__ rmax,
    float* __restrict__ XP) {
  int b = blockIdx.x >> 3, kc = blockIdx.x & 7;
  int kbase = kc * 512;
  __shared__ short la[64][40];
  __shared__ short lb[256][40];
  int t = threadIdx.x, w = t >> 6, l = t & 63;
  int lrow = l & 15, lk = (l >> 4) * 8;

  f32x4 zero = {0.f, 0.f, 0.f, 0.f};
  f32x4 acc[4][4];
#pragma unroll
  for (int i = 0; i < 4; ++i)
#pragma unroll
    for (int j = 0; j < 4; ++j) acc[i][j] = zero;

  for (int ks = 0; ks < 16; ++ks) {
    int k0 = kbase + ks * 32;
    __syncthreads();
    {   // stage A: exp(K - rmax), 64 rows x 32
      int r = t >> 2, sg = (t & 3) * 8;
      const float4* src = (const float4*)(Kb + ((size_t)(b * UK + r)) * MM + k0 + sg);
      float rm = rmax[b * UK + r];
      s16x8 wv;
#pragma unroll
      for (int i = 0; i < 2; ++i) {
        float4 v = src[i];
        wv[i * 4 + 0] = f2bf(__expf(v.x - rm));
        wv[i * 4 + 1] = f2bf(__expf(v.y - rm));
        wv[i * 4 + 2] = f2bf(__expf(v.z - rm));
        wv[i * 4 + 3] = f2bf(__expf(v.w - rm));
      }
      *(s16x8*)&la[r][sg] = wv;
    }
#pragma unroll
    for (int it = 0; it < 8; ++it) {   // stage B: x, 256 rows x 32
      int r = (t >> 3) + it * 32, sg = (t & 7) * 4;
      float4 v = *(const float4*)(x + ((size_t)(b * CC + r)) * MM + k0 + sg);
      s16x4 wv;
      wv[0] = f2bf(v.x); wv[1] = f2bf(v.y); wv[2] = f2bf(v.z); wv[3] = f2bf(v.w);
      *(s16x4*)&lb[r][sg] = wv;
    }
    __syncthreads();
    s16x8 af[4], bfr[4];
#pragma unroll
    for (int i = 0; i < 4; ++i) af[i] = *(const s16x8*)&la[i * 16 + lrow][lk];
#pragma unroll
    for (int j = 0; j < 4; ++j) bfr[j] = *(const s16x8*)&lb[w * 64 + j * 16 + lrow][lk];
#pragma unroll
    for (int i = 0; i < 4; ++i)
#pragma unroll
      for (int j = 0; j < 4; ++j)
        acc[i][j] = __builtin_amdgcn_mfma_f32_16x16x32_bf16(af[i], bfr[j], acc[i][j], 0, 0, 0);
  }
#pragma unroll
  for (int i = 0; i < 4; ++i)
#pragma unroll
    for (int j = 0; j < 4; ++j)
#pragma unroll
      for (int r = 0; r < 4; ++r) {
        int row = i * 16 + (l >> 4) * 4 + r;       // j index 0..63
        int col = w * 64 + j * 16 + lrow;          // c index 0..255
        atomicAdd(&XP[((size_t)b * UK + row) * CC + col], acc[i][j][r]);
      }
}

// ---------------- ctx[b,kk,vv] = sum_u aV*(Wv . xp_n + bv) + bVa ----------------
__global__ __launch_bounds__(256) void k_ctx(const float* __restrict__ XP,
    const float* __restrict__ rsum,
    const float* __restrict__ Wv, const float* __restrict__ bv,
    const float* __restrict__ AV, const float* __restrict__ BVa,
    float* __restrict__ CTX) {
  int b = blockIdx.x >> 4, kk = blockIdx.x & 15;
  __shared__ float lxp[4][256];
  int t = threadIdx.x;
#pragma unroll
  for (int u = 0; u < 4; ++u) {
    int row = b * UK + u * KD + kk;
    lxp[u][t] = XP[(size_t)row * CC + t] / rsum[row];
  }
  __syncthreads();
  float acc = 0.f;
#pragma unroll
  for (int u = 0; u < 4; ++u) {
    int ch = u * 256 + t;
    const float4* wv4 = (const float4*)(Wv + (size_t)ch * CC);
    float dot = 0.f;
#pragma unroll 8
    for (int c4 = 0; c4 < 64; ++c4) {
      float4 wv = wv4[c4];
      dot += wv.x * lxp[u][c4 * 4 + 0] + wv.y * lxp[u][c4 * 4 + 1] +
             wv.z * lxp[u][c4 * 4 + 2] + wv.w * lxp[u][c4 * 4 + 3];
    }
    acc += AV[ch] * (dot + bv[ch]) + BVa[ch];
  }
  CTX[((size_t)b * KD + kk) * 256 + t] = acc;
}

// ---------------- y[b,vv,m] = sum_kk (aQ*Q+bQ)[kk,m] * ctx[kk,vv] ----------------
__global__ __launch_bounds__(256) void k_y(const float* __restrict__ Qb,
    const float* __restrict__ CTX,
    const float* __restrict__ AQ, const float* __restrict__ BQa,
    float* __restrict__ y) {
  int b = blockIdx.x >> 4, nc = blockIdx.x & 15;
  int m = nc * 256 + threadIdx.x;
  float qn[16];
#pragma unroll
  for (int kk = 0; kk < 16; ++kk)
    qn[kk] = AQ[kk] * Qb[((size_t)b * KD + kk) * MM + m] + BQa[kk];
  const float* cb = CTX + (size_t)b * KD * 256;
  float* yo = y + (size_t)b * 256 * MM + m;
#pragma unroll 4
  for (int vv = 0; vv < 256; ++vv) {
    float acc = 0.f;
#pragma unroll
    for (int kk = 0; kk < 16; ++kk)
      acc = fmaf(qn[kk], cb[kk * 256 + vv], acc);   // uniform -> scalar loads
    yo[(size_t)vv * MM] = acc;
  }
}

extern "C" void kernel_launch(void* const* d_in, const int* in_sizes, int n_in,
                              void* d_out, int out_size, void* d_ws, size_t ws_size,
                              hipStream_t stream) {
  const float* x   = (const float*)d_in[0];
  const float* Wq  = (const float*)d_in[1];
  const float* bq  = (const float*)d_in[2];
  const float* Wk  = (const float*)d_in[3];
  const float* bk  = (const float*)d_in[4];
  const float* Wv  = (const float*)d_in[5];
  const float* bv  = (const float*)d_in[6];
  const float* gq  = (const float*)d_in[7];
  const float* btq = (const float*)d_in[8];
  const float* gv  = (const float*)d_in[9];
  const float* btv = (const float*)d_in[10];
  float* out = (float*)d_out;
  float* ws  = (float*)d_ws;

  // workspace layout (f32 elements)
  float* G    = ws;                 // 65536
  float* XP   = ws + 65536;         // 262144
  float* XSUM = ws + 327680;        // 256
  float* RMAX = ws + 327936;        // 1024
  float* RSUM = ws + 328960;        // 1024
  float* AV   = ws + 329984;        // 1024
  float* BVa  = ws + 331008;        // 1024
  float* AQ   = ws + 332032;        // 16
  float* BQa  = ws + 332048;        // 16 (pad to 332288)
  float* CTX  = ws + 332288;        // 65536
  float* KB   = ws + 397824;        // 4194304
  float* QB   = ws + 4592128;       // 1048576  -> total ~22.6 MB

  // zero the atomically-accumulated buffers (G, XP, XSUM are contiguous)
  hipMemsetAsync(ws, 0, (size_t)(65536 + 262144 + 256) * sizeof(float), stream);

  k_xsum  <<<4096, 256, 0, stream>>>(x, XSUM);
  k_proj  <<<256,  256, 0, stream>>>(x, Wq, bq, Wk, bk, KB, QB);
  k_gxx   <<<128,  512, 0, stream>>>(x, G);
  k_sstats<<<1024, 256, 0, stream>>>(KB, RMAX, RSUM);
  k_fin   <<<1040, 256, 0, stream>>>(G, XSUM, Wv, bv, gv, btv, Wq, bq, gq, btq,
                                     AV, BVa, AQ, BQa);
  k_xp    <<<128,  256, 0, stream>>>(x, KB, RMAX, XP);
  k_ctx   <<<256,  256, 0, stream>>>(XP, RSUM, Wv, bv, AV, BVa, CTX);
  k_y     <<<256,  256, 0, stream>>>(QB, CTX, AQ, BQa, out);
}

// Round 2
// 218.556 us; speedup vs baseline: 1.5907x; 1.5907x over previous
//
#include <hip/hip_runtime.h>
#include <hip/hip_bf16.h>

typedef short s16x8 __attribute__((ext_vector_type(8)));
typedef short s16x4 __attribute__((ext_vector_type(4)));
typedef float f32x4 __attribute__((ext_vector_type(4)));
typedef unsigned u32;

#define DI __device__ __forceinline__

constexpr int BB = 16;    // batch
constexpr int CC = 256;   // in channels
constexpr int MM = 4096;  // H*W
constexpr int KD = 16;    // k
constexpr int UK = 64;    // u*k
constexpr float EPSV = 1e-5f;

DI unsigned short f2bf(float f) {
  union { float f; unsigned u; } v; v.f = f;
  unsigned r = v.u + 0x7FFFu + ((v.u >> 16) & 1u);
  return (unsigned short)(r >> 16);
}

// ---------------- xsum[c] = sum over b,m of x[b,c,m] ----------------
__global__ __launch_bounds__(256) void k_xsum(const float* __restrict__ x,
                                              float* __restrict__ xsum) {
  int bid = blockIdx.x;                 // 0..4095 = b*256 + c
  int b = bid >> 8, c = bid & 255;
  const float4* p = (const float4*)(x + ((size_t)(b * CC + c)) * MM);
  int t = threadIdx.x;
  float s = 0.f;
#pragma unroll
  for (int i = 0; i < 4; ++i) {
    float4 v = p[i * 256 + t];
    s += v.x + v.y + v.z + v.w;
  }
#pragma unroll
  for (int o = 32; o; o >>= 1) s += __shfl_down(s, o);
  __shared__ float red[4];
  if ((t & 63) == 0) red[t >> 6] = s;
  __syncthreads();
  if (t == 0) atomicAdd(&xsum[c], red[0] + red[1] + red[2] + red[3]);
}

// ---------------- Q/K projection via bf16 MFMA ----------------
// P[o,m] = sum_c W[o,c] x[c,m];  o: 0..63 = K rows (Wk), 64..79 = Q rows (Wq)
// A-frag: W rows (k=c contiguous in memory). B-frag: needs x^T[m][c] -> built
// during LDS staging (channel-pair packed into u32, pitch 17 words).
__global__ __launch_bounds__(256) void k_proj(const float* __restrict__ x,
    const float* __restrict__ Wq, const float* __restrict__ bq,
    const float* __restrict__ Wk, const float* __restrict__ bk,
    float* __restrict__ Kb, float* __restrict__ Qb) {
  int b = blockIdx.x >> 5, mc = blockIdx.x & 31;   // 16 b * 32 m-chunks
  int gm0 = mc * 128;
  __shared__ short wlds[80 * 264];                 // W bf16, pitch 264 (528B, 16B-aligned)
  __shared__ u32 xt[128 * 17];                     // x^T tile: [m][c-pair], pitch 17 words
  int t = threadIdx.x;
  int w = t >> 6, l = t & 63;
  int lrow = l & 15, lk = l >> 4;                  // lk in 0..3

  // preload all of W (bf16) into LDS
#pragma unroll 4
  for (int o = 0; o < 80; ++o) {
    float v = (o < 64) ? Wk[o * CC + t] : Wq[(o - 64) * CC + t];
    wlds[o * 264 + t] = (short)f2bf(v);
  }

  f32x4 acc[5][2];
#pragma unroll
  for (int i = 0; i < 5; ++i) { acc[i][0] = (f32x4)0.f; acc[i][1] = (f32x4)0.f; }

  int c2 = t >> 4;          // c-pair column 0..15
  int mq = t & 15;          // m quad index

  for (int ks = 0; ks < 8; ++ks) {
    int c0 = ks * 32;
    __syncthreads();
    // stage x^T: 32 channels x 128 m, packed as bf16 pairs
#pragma unroll
    for (int mb = 0; mb < 128; mb += 64) {
      int m = mb + mq * 4;
      const float* p0 = x + ((size_t)(b * CC + c0 + 2 * c2)) * MM + gm0 + m;
      float4 v0 = *(const float4*)p0;
      float4 v1 = *(const float4*)(p0 + MM);
      xt[(m + 0) * 17 + c2] = (u32)f2bf(v0.x) | ((u32)f2bf(v1.x) << 16);
      xt[(m + 1) * 17 + c2] = (u32)f2bf(v0.y) | ((u32)f2bf(v1.y) << 16);
      xt[(m + 2) * 17 + c2] = (u32)f2bf(v0.z) | ((u32)f2bf(v1.z) << 16);
      xt[(m + 3) * 17 + c2] = (u32)f2bf(v0.w) | ((u32)f2bf(v1.w) << 16);
    }
    __syncthreads();
    union { s16x8 v; u32 wd[4]; } bfr[2];
#pragma unroll
    for (int j = 0; j < 2; ++j) {
      int ml = w * 32 + j * 16 + lrow;
#pragma unroll
      for (int i = 0; i < 4; ++i) bfr[j].wd[i] = xt[ml * 17 + lk * 4 + i];
    }
#pragma unroll
    for (int ot = 0; ot < 5; ++ot) {
      s16x8 af = *(const s16x8*)&wlds[(ot * 16 + lrow) * 264 + c0 + lk * 8];
      acc[ot][0] = __builtin_amdgcn_mfma_f32_16x16x32_bf16(af, bfr[0].v, acc[ot][0], 0, 0, 0);
      acc[ot][1] = __builtin_amdgcn_mfma_f32_16x16x32_bf16(af, bfr[1].v, acc[ot][1], 0, 0, 0);
    }
  }

  // epilogue: D lane l reg r -> row o = ot*16 + lk*4 + r, col m = w*32 + j*16 + lrow
#pragma unroll
  for (int ot = 0; ot < 5; ++ot)
#pragma unroll
    for (int j = 0; j < 2; ++j)
#pragma unroll
      for (int r = 0; r < 4; ++r) {
        int o = ot * 16 + lk * 4 + r;
        int m = gm0 + w * 32 + j * 16 + lrow;
        float val = acc[ot][j][r];
        if (o < 64) Kb[((size_t)(b * UK + o)) * MM + m] = val + bk[o];
        else        Qb[((size_t)(b * KD + o - 64)) * MM + m] = val + bq[o - 64];
      }
}

// ---------------- G = sum_b x[b] x[b]^T  (bf16 MFMA, atomic accumulate) ----------------
__global__ __launch_bounds__(512) void k_gxx(const float* __restrict__ x,
                                             float* __restrict__ G) {
  int b = blockIdx.x >> 3, kc = blockIdx.x & 7;   // 16 b * 8 k-chunks of 512
  int kbase = kc * 512;
  __shared__ short lt[256][40];                   // 32 bf16 + pad 8
  int t = threadIdx.x;
  int w = t >> 6, l = t & 63;
  int wr = w >> 2, wc = w & 3;                    // wave tile: rows 128*wr, cols 64*wc
  int lrow = l & 15, lk = (l >> 4) * 8;

  f32x4 zero = {0.f, 0.f, 0.f, 0.f};
  f32x4 acc[8][4];
#pragma unroll
  for (int i = 0; i < 8; ++i)
#pragma unroll
    for (int j = 0; j < 4; ++j) acc[i][j] = zero;

  for (int ks = 0; ks < 16; ++ks) {
    int k0 = kbase + ks * 32;
    __syncthreads();
    {
      int r = t >> 1, hh = (t & 1) * 16;
      const float4* src = (const float4*)(x + ((size_t)(b * CC + r)) * MM + k0 + hh);
      s16x8 w0, w1;
#pragma unroll
      for (int i = 0; i < 2; ++i) {
        float4 v = src[i];
        w0[i * 4 + 0] = f2bf(v.x); w0[i * 4 + 1] = f2bf(v.y);
        w0[i * 4 + 2] = f2bf(v.z); w0[i * 4 + 3] = f2bf(v.w);
      }
#pragma unroll
      for (int i = 0; i < 2; ++i) {
        float4 v = src[2 + i];
        w1[i * 4 + 0] = f2bf(v.x); w1[i * 4 + 1] = f2bf(v.y);
        w1[i * 4 + 2] = f2bf(v.z); w1[i * 4 + 3] = f2bf(v.w);
      }
      *(s16x8*)&lt[r][hh] = w0;
      *(s16x8*)&lt[r][hh + 8] = w1;
    }
    __syncthreads();
    s16x8 af[8], bf[4];
#pragma unroll
    for (int i = 0; i < 8; ++i) af[i] = *(const s16x8*)&lt[wr * 128 + i * 16 + lrow][lk];
#pragma unroll
    for (int j = 0; j < 4; ++j) bf[j] = *(const s16x8*)&lt[wc * 64 + j * 16 + lrow][lk];
#pragma unroll
    for (int i = 0; i < 8; ++i)
#pragma unroll
      for (int j = 0; j < 4; ++j)
        acc[i][j] = __builtin_amdgcn_mfma_f32_16x16x32_bf16(af[i], bf[j], acc[i][j], 0, 0, 0);
  }
#pragma unroll
  for (int i = 0; i < 8; ++i)
#pragma unroll
    for (int j = 0; j < 4; ++j)
#pragma unroll
      for (int r = 0; r < 4; ++r) {
        int row = wr * 128 + i * 16 + (l >> 4) * 4 + r;
        int col = wc * 64 + j * 16 + lrow;
        atomicAdd(&G[row * 256 + col], acc[i][j][r]);
      }
}

// ---------------- softmax row stats over K ----------------
__global__ __launch_bounds__(256) void k_sstats(const float* __restrict__ Kb,
    float* __restrict__ rmax, float* __restrict__ rsum) {
  int r = blockIdx.x;                    // 0..1023
  int t = threadIdx.x;
  const float4* p = (const float4*)(Kb + (size_t)r * MM);
  float4 v[4];
  float mx = -3.4e38f;
#pragma unroll
  for (int i = 0; i < 4; ++i) {
    v[i] = p[i * 256 + t];
    mx = fmaxf(mx, fmaxf(fmaxf(v[i].x, v[i].y), fmaxf(v[i].z, v[i].w)));
  }
#pragma unroll
  for (int o = 32; o; o >>= 1) mx = fmaxf(mx, __shfl_xor(mx, o));
  __shared__ float red[4];
  int w = t >> 6;
  if ((t & 63) == 0) red[w] = mx;
  __syncthreads();
  mx = fmaxf(fmaxf(red[0], red[1]), fmaxf(red[2], red[3]));
  float s = 0.f;
#pragma unroll
  for (int i = 0; i < 4; ++i)
    s += __expf(v[i].x - mx) + __expf(v[i].y - mx) +
         __expf(v[i].z - mx) + __expf(v[i].w - mx);
#pragma unroll
  for (int o = 32; o; o >>= 1) s += __shfl_xor(s, o);
  __syncthreads();
  if ((t & 63) == 0) red[w] = s;
  __syncthreads();
  if (t == 0) {
    rmax[r] = mx;
    rsum[r] = red[0] + red[1] + red[2] + red[3];
  }
}

// ---------------- BN affine params from G, xsum ----------------
__global__ __launch_bounds__(256) void k_fin(const float* __restrict__ G,
    const float* __restrict__ xsum,
    const float* __restrict__ Wv, const float* __restrict__ bv,
    const float* __restrict__ gv, const float* __restrict__ btv,
    const float* __restrict__ Wq, const float* __restrict__ bq,
    const float* __restrict__ gq, const float* __restrict__ btq,
    float* __restrict__ AV, float* __restrict__ BVa,
    float* __restrict__ AQ, float* __restrict__ BQa) {
  int o = blockIdx.x;                    // 0..1039: 0..1023 V-ch, 1024.. Q-ch
  int t = threadIdx.x;
  const float* w; float bias, gamma, beta; float* pa; float* pb;
  if (o < 1024) {
    w = Wv + (size_t)o * CC; bias = bv[o]; gamma = gv[o]; beta = btv[o];
    pa = AV + o; pb = BVa + o;
  } else {
    int oi = o - 1024;
    w = Wq + (size_t)oi * CC; bias = bq[oi]; gamma = gq[oi]; beta = btq[oi];
    pa = AQ + oi; pb = BQa + oi;
  }
  __shared__ float lw[256];
  lw[t] = w[t];
  __syncthreads();
  const float* g = G + (size_t)t * CC;
  float tv = 0.f;
#pragma unroll 8
  for (int c = 0; c < CC; c += 4) {
    float4 g4 = *(const float4*)(g + c);
    tv += g4.x * lw[c] + g4.y * lw[c + 1] + g4.z * lw[c + 2] + g4.w * lw[c + 3];
  }
  float qf = tv * lw[t];
  float sx = lw[t] * xsum[t];
#pragma unroll
  for (int od = 32; od; od >>= 1) { qf += __shfl_xor(qf, od); sx += __shfl_xor(sx, od); }
  __shared__ float r1[4], r2[4];
  int wv = t >> 6;
  if ((t & 63) == 0) { r1[wv] = qf; r2[wv] = sx; }
  __syncthreads();
  if (t == 0) {
    qf = r1[0] + r1[1] + r1[2] + r1[3];
    sx = r2[0] + r2[1] + r2[2] + r2[3];
    const float invN = 1.f / 65536.f;
    float mean = sx * invN + bias;
    float e2 = qf * invN + 2.f * bias * sx * invN + bias * bias;
    float var = e2 - mean * mean;
    float a = gamma * rsqrtf(var + EPSV);
    *pa = a;
    *pb = beta - mean * a;
  }
}

// ---------------- xp[b,j,c] = sum_m exp(K[b,j,m]-rmax) * x[b,c,m]  (bf16 MFMA) ----------------
__global__ __launch_bounds__(256) void k_xp(const float* __restrict__ x,
    const float* __restrict__ Kb, const float* __restrict__ rmax,
    float* __restrict__ XP) {
  int b = blockIdx.x >> 3, kc = blockIdx.x & 7;
  int kbase = kc * 512;
  __shared__ short la[64][40];
  __shared__ short lb[256][40];
  int t = threadIdx.x, w = t >> 6, l = t & 63;
  int lrow = l & 15, lk = (l >> 4) * 8;

  f32x4 zero = {0.f, 0.f, 0.f, 0.f};
  f32x4 acc[4][4];
#pragma unroll
  for (int i = 0; i < 4; ++i)
#pragma unroll
    for (int j = 0; j < 4; ++j) acc[i][j] = zero;

  for (int ks = 0; ks < 16; ++ks) {
    int k0 = kbase + ks * 32;
    __syncthreads();
    {   // stage A: exp(K - rmax), 64 rows x 32
      int r = t >> 2, sg = (t & 3) * 8;
      const float4* src = (const float4*)(Kb + ((size_t)(b * UK + r)) * MM + k0 + sg);
      float rm = rmax[b * UK + r];
      s16x8 wv;
#pragma unroll
      for (int i = 0; i < 2; ++i) {
        float4 v = src[i];
        wv[i * 4 + 0] = f2bf(__expf(v.x - rm));
        wv[i * 4 + 1] = f2bf(__expf(v.y - rm));
        wv[i * 4 + 2] = f2bf(__expf(v.z - rm));
        wv[i * 4 + 3] = f2bf(__expf(v.w - rm));
      }
      *(s16x8*)&la[r][sg] = wv;
    }
#pragma unroll
    for (int it = 0; it < 8; ++it) {   // stage B: x, 256 rows x 32
      int r = (t >> 3) + it * 32, sg = (t & 7) * 4;
      float4 v = *(const float4*)(x + ((size_t)(b * CC + r)) * MM + k0 + sg);
      s16x4 wv;
      wv[0] = f2bf(v.x); wv[1] = f2bf(v.y); wv[2] = f2bf(v.z); wv[3] = f2bf(v.w);
      *(s16x4*)&lb[r][sg] = wv;
    }
    __syncthreads();
    s16x8 af[4], bfr[4];
#pragma unroll
    for (int i = 0; i < 4; ++i) af[i] = *(const s16x8*)&la[i * 16 + lrow][lk];
#pragma unroll
    for (int j = 0; j < 4; ++j) bfr[j] = *(const s16x8*)&lb[w * 64 + j * 16 + lrow][lk];
#pragma unroll
    for (int i = 0; i < 4; ++i)
#pragma unroll
      for (int j = 0; j < 4; ++j)
        acc[i][j] = __builtin_amdgcn_mfma_f32_16x16x32_bf16(af[i], bfr[j], acc[i][j], 0, 0, 0);
  }
#pragma unroll
  for (int i = 0; i < 4; ++i)
#pragma unroll
    for (int j = 0; j < 4; ++j)
#pragma unroll
      for (int r = 0; r < 4; ++r) {
        int row = i * 16 + (l >> 4) * 4 + r;       // j index 0..63
        int col = w * 64 + j * 16 + lrow;          // c index 0..255
        atomicAdd(&XP[((size_t)b * UK + row) * CC + col], acc[i][j][r]);
      }
}

// ---------------- ctx[b,kk,vv] = sum_u aV*(Wv . xp_n + bv) + bVa ----------------
__global__ __launch_bounds__(256) void k_ctx(const float* __restrict__ XP,
    const float* __restrict__ rsum,
    const float* __restrict__ Wv, const float* __restrict__ bv,
    const float* __restrict__ AV, const float* __restrict__ BVa,
    float* __restrict__ CTX) {
  int b = blockIdx.x >> 4, kk = blockIdx.x & 15;
  __shared__ float lxp[4][256];
  int t = threadIdx.x;
#pragma unroll
  for (int u = 0; u < 4; ++u) {
    int row = b * UK + u * KD + kk;
    lxp[u][t] = XP[(size_t)row * CC + t] / rsum[row];
  }
  __syncthreads();
  float acc = 0.f;
#pragma unroll
  for (int u = 0; u < 4; ++u) {
    int ch = u * 256 + t;
    const float4* wv4 = (const float4*)(Wv + (size_t)ch * CC);
    float dot = 0.f;
#pragma unroll 8
    for (int c4 = 0; c4 < 64; ++c4) {
      float4 wv = wv4[c4];
      dot += wv.x * lxp[u][c4 * 4 + 0] + wv.y * lxp[u][c4 * 4 + 1] +
             wv.z * lxp[u][c4 * 4 + 2] + wv.w * lxp[u][c4 * 4 + 3];
    }
    acc += AV[ch] * (dot + bv[ch]) + BVa[ch];
  }
  CTX[((size_t)b * KD + kk) * 256 + t] = acc;
}

// ---------------- y[b,vv,m] = sum_kk (aQ*Q+bQ)[kk,m] * ctx[kk,vv] ----------------
__global__ __launch_bounds__(256) void k_y(const float* __restrict__ Qb,
    const float* __restrict__ CTX,
    const float* __restrict__ AQ, const float* __restrict__ BQa,
    float* __restrict__ y) {
  int b = blockIdx.x >> 4, nc = blockIdx.x & 15;
  int m = nc * 256 + threadIdx.x;
  float qn[16];
#pragma unroll
  for (int kk = 0; kk < 16; ++kk)
    qn[kk] = AQ[kk] * Qb[((size_t)b * KD + kk) * MM + m] + BQa[kk];
  const float* cb = CTX + (size_t)b * KD * 256;
  float* yo = y + (size_t)b * 256 * MM + m;
#pragma unroll 4
  for (int vv = 0; vv < 256; ++vv) {
    float acc = 0.f;
#pragma unroll
    for (int kk = 0; kk < 16; ++kk)
      acc = fmaf(qn[kk], cb[kk * 256 + vv], acc);   // uniform -> scalar loads
    yo[(size_t)vv * MM] = acc;
  }
}

extern "C" void kernel_launch(void* const* d_in, const int* in_sizes, int n_in,
                              void* d_out, int out_size, void* d_ws, size_t ws_size,
                              hipStream_t stream) {
  const float* x   = (const float*)d_in[0];
  const float* Wq  = (const float*)d_in[1];
  const float* bq  = (const float*)d_in[2];
  const float* Wk  = (const float*)d_in[3];
  const float* bk  = (const float*)d_in[4];
  const float* Wv  = (const float*)d_in[5];
  const float* bv  = (const float*)d_in[6];
  const float* gq  = (const float*)d_in[7];
  const float* btq = (const float*)d_in[8];
  const float* gv  = (const float*)d_in[9];
  const float* btv = (const float*)d_in[10];
  float* out = (float*)d_out;
  float* ws  = (float*)d_ws;

  // workspace layout (f32 elements)
  float* G    = ws;                 // 65536
  float* XP   = ws + 65536;         // 262144
  float* XSUM = ws + 327680;        // 256
  float* RMAX = ws + 327936;        // 1024
  float* RSUM = ws + 328960;        // 1024
  float* AV   = ws + 329984;        // 1024
  float* BVa  = ws + 331008;        // 1024
  float* AQ   = ws + 332032;        // 16
  float* BQa  = ws + 332048;        // 16 (pad to 332288)
  float* CTX  = ws + 332288;        // 65536
  float* KB   = ws + 397824;        // 4194304
  float* QB   = ws + 4592128;       // 1048576  -> total ~22.6 MB

  // zero the atomically-accumulated buffers (G, XP, XSUM are contiguous)
  hipMemsetAsync(ws, 0, (size_t)(65536 + 262144 + 256) * sizeof(float), stream);

  k_xsum  <<<4096, 256, 0, stream>>>(x, XSUM);
  k_proj  <<<512,  256, 0, stream>>>(x, Wq, bq, Wk, bk, KB, QB);
  k_gxx   <<<128,  512, 0, stream>>>(x, G);
  k_sstats<<<1024, 256, 0, stream>>>(KB, RMAX, RSUM);
  k_fin   <<<1040, 256, 0, stream>>>(G, XSUM, Wv, bv, gv, btv, Wq, bq, gq, btq,
                                     AV, BVa, AQ, BQa);
  k_xp    <<<128,  256, 0, stream>>>(x, KB, RMAX, XP);
  k_ctx   <<<256,  256, 0, stream>>>(XP, RSUM, Wv, bv, AV, BVa, CTX);
  k_y     <<<256,  256, 0, stream>>>(QB, CTX, AQ, BQa, out);
}